// Round 1
// baseline (2409.502 us; speedup 1.0000x reference)
//
#include <hip/hip_runtime.h>

#define N_NODES 100000
#define N_EDGES 800000
#define N_ETYPES 5
#define NUM_GRAPHS 64
#define IN_DIM 23
#define HID_DIM 128
#define OUT_DIM 64

// ---------------- degree count (all etypes at once) ----------------
__global__ __launch_bounds__(256) void k_deg(const int* __restrict__ edges,
                                             float* __restrict__ deg) {
    int e = blockIdx.x * 256 + threadIdx.x;
    int t = blockIdx.y;
    if (e < N_EDGES) {
        int d = edges[((size_t)t * 2 + 1) * N_EDGES + e];
        atomicAdd(&deg[t * N_NODES + d], 1.0f);
    }
}

// ---------------- layer-1 scatter: thread = (edge, feature) ----------------
__global__ __launch_bounds__(256) void k_scatter1(const int* __restrict__ src,
                                                  const int* __restrict__ dst,
                                                  const float* __restrict__ x,
                                                  float* __restrict__ neigh) {
    int idx = blockIdx.x * 256 + threadIdx.x;        // up to 18.4M
    if (idx >= N_EDGES * IN_DIM) return;
    int e = idx / IN_DIM;
    int f = idx - e * IN_DIM;
    atomicAdd(&neigh[(size_t)dst[e] * IN_DIM + f], x[(size_t)src[e] * IN_DIM + f]);
}

// ---------------- layer-1 fused (neigh+x)/(deg+1) @ W1, += into h1 ----------------
#define G1_NODES 8
__global__ __launch_bounds__(128) void k_gemm1(const float* __restrict__ neigh,
                                               const float* __restrict__ x,
                                               const float* __restrict__ deg,
                                               const float* __restrict__ W1,
                                               float* __restrict__ h1) {
    __shared__ float a[IN_DIM];
    int j = threadIdx.x;                              // 0..127
    int n0 = blockIdx.x * G1_NODES;
    for (int k = 0; k < G1_NODES; ++k) {
        int n = n0 + k;
        if (j < IN_DIM) {
            float inv = 1.0f / (deg[n] + 1.0f);
            a[j] = (neigh[(size_t)n * IN_DIM + j] + x[(size_t)n * IN_DIM + j]) * inv;
        }
        __syncthreads();
        float acc = 0.f;
        #pragma unroll
        for (int f = 0; f < IN_DIM; ++f)
            acc = fmaf(a[f], W1[f * HID_DIM + j], acc);
        h1[(size_t)n * HID_DIM + j] += acc;
        __syncthreads();
    }
}

// ---------------- bias-sum + ReLU on h1 ----------------
__global__ __launch_bounds__(256) void k_relu(float* __restrict__ h1,
                                              const float* __restrict__ b1) {
    int idx = blockIdx.x * 256 + threadIdx.x;        // N*128 = 12.8M
    if (idx >= N_NODES * HID_DIM) return;
    int j = idx & (HID_DIM - 1);
    float b = 0.f;
    #pragma unroll
    for (int t = 0; t < N_ETYPES; ++t) b += b1[t * HID_DIM + j];
    float v = h1[idx] + b;
    h1[idx] = v > 0.f ? v : 0.f;
}

// ---------------- layer-2 GEMM: g = h1 @ W2[t]  (128 -> 64) ----------------
#define G2_ROWS_ITER 4
#define G2_ITERS 8            // 32 rows per block
__global__ __launch_bounds__(256) void k_gemm2(const float* __restrict__ h1,
                                               const float* __restrict__ W2,
                                               float* __restrict__ g) {
    __shared__ float w[HID_DIM * OUT_DIM];           // 32 KiB
    __shared__ float a[G2_ROWS_ITER * HID_DIM];      // 2 KiB
    for (int i = threadIdx.x; i < HID_DIM * OUT_DIM; i += 256)
        w[i] = W2[i];
    int r = threadIdx.x >> 6;                        // 0..3
    int j = threadIdx.x & 63;                        // 0..63
    int base = blockIdx.x * (G2_ROWS_ITER * G2_ITERS);
    for (int it = 0; it < G2_ITERS; ++it) {
        int n0 = base + it * G2_ROWS_ITER;
        __syncthreads();                             // w ready / prev compute done
        for (int i = threadIdx.x; i < G2_ROWS_ITER * HID_DIM; i += 256) {
            int rr = i >> 7, ff = i & 127;
            int n = n0 + rr;
            a[i] = (n < N_NODES) ? h1[(size_t)n * HID_DIM + ff] : 0.f;
        }
        __syncthreads();
        int n = n0 + r;
        if (n < N_NODES) {
            float acc = 0.f;
            #pragma unroll
            for (int f = 0; f < HID_DIM; ++f)
                acc = fmaf(a[r * HID_DIM + f], w[f * OUT_DIM + j], acc);
            g[(size_t)n * OUT_DIM + j] = acc;
        }
    }
}

// ---------------- layer-2 scatter: wave = edge, lane = feature ----------------
__global__ __launch_bounds__(256) void k_scatter2(const int* __restrict__ src,
                                                  const int* __restrict__ dst,
                                                  const float* __restrict__ g,
                                                  float* __restrict__ neigh) {
    int idx = blockIdx.x * 256 + threadIdx.x;        // E*64 = 51.2M
    int e = idx >> 6;
    int f = idx & 63;
    if (e < N_EDGES)
        atomicAdd(&neigh[(size_t)dst[e] * OUT_DIM + f],
                  g[(size_t)src[e] * OUT_DIM + f]);
}

// ---------------- layer-2 accumulate into h2 ----------------
__global__ __launch_bounds__(256) void k_accum2(const float* __restrict__ neigh,
                                                const float* __restrict__ g,
                                                const float* __restrict__ deg,
                                                float* __restrict__ h2) {
    int idx = blockIdx.x * 256 + threadIdx.x;        // N*64 = 6.4M
    if (idx >= N_NODES * OUT_DIM) return;
    int n = idx >> 6;
    float inv = 1.0f / (deg[n] + 1.0f);
    h2[idx] += (neigh[idx] + g[idx]) * inv;
}

// ---------------- pooling: block = graph, binary-search sorted graph_ids ----------------
__global__ __launch_bounds__(256) void k_pool(const float* __restrict__ h2,
                                              const int* __restrict__ gids,
                                              const float* __restrict__ b2,
                                              float* __restrict__ out) {
    __shared__ float red[4][OUT_DIM];
    int gid = blockIdx.x;
    int lo = 0, hi = N_NODES;
    while (lo < hi) { int mid = (lo + hi) >> 1; if (gids[mid] < gid) lo = mid + 1; else hi = mid; }
    int start = lo;
    hi = N_NODES;
    while (lo < hi) { int mid = (lo + hi) >> 1; if (gids[mid] < gid + 1) lo = mid + 1; else hi = mid; }
    int end = lo;
    int count = end - start;
    int r = threadIdx.x >> 6, j = threadIdx.x & 63;
    float acc = 0.f;
    for (int n = start + r; n < end; n += 4)
        acc += h2[(size_t)n * OUT_DIM + j];
    red[r][j] = acc;
    __syncthreads();
    if (r == 0) {
        float total = red[0][j] + red[1][j] + red[2][j] + red[3][j];
        float b = 0.f;
        #pragma unroll
        for (int t = 0; t < N_ETYPES; ++t) b += b2[t * OUT_DIM + j];
        float c = (float)count;
        out[gid * OUT_DIM + j] = (total + c * b) / fmaxf(c, 1.0f);
    }
}

extern "C" void kernel_launch(void* const* d_in, const int* in_sizes, int n_in,
                              void* d_out, int out_size, void* d_ws, size_t ws_size,
                              hipStream_t stream) {
    const float* x    = (const float*)d_in[0];
    const int*   edges= (const int*)d_in[1];
    const int*   gids = (const int*)d_in[2];
    const float* W1   = (const float*)d_in[3];
    const float* b1   = (const float*)d_in[4];
    const float* W2   = (const float*)d_in[5];
    const float* b2   = (const float*)d_in[6];
    float* out = (float*)d_out;

    float* ws    = (float*)d_ws;
    float* deg   = ws;                                   // 5*N
    float* h1    = deg + (size_t)N_ETYPES * N_NODES;     // N*128
    float* h2    = h1  + (size_t)N_NODES * HID_DIM;      // N*64
    float* g     = h2  + (size_t)N_NODES * OUT_DIM;      // N*64
    float* neigh = g   + (size_t)N_NODES * OUT_DIM;      // N*64 (N*23 used in layer 1)

    hipMemsetAsync(deg, 0, (size_t)N_ETYPES * N_NODES * 4, stream);
    hipMemsetAsync(h1,  0, (size_t)N_NODES * HID_DIM * 4, stream);
    hipMemsetAsync(h2,  0, (size_t)N_NODES * OUT_DIM * 4, stream);

    dim3 gdeg((N_EDGES + 255) / 256, N_ETYPES);
    k_deg<<<gdeg, 256, 0, stream>>>(edges, deg);

    for (int t = 0; t < N_ETYPES; ++t) {
        const int* src = edges + (size_t)(t * 2 + 0) * N_EDGES;
        const int* dst = edges + (size_t)(t * 2 + 1) * N_EDGES;
        hipMemsetAsync(neigh, 0, (size_t)N_NODES * IN_DIM * 4, stream);
        k_scatter1<<<(N_EDGES * IN_DIM + 255) / 256, 256, 0, stream>>>(src, dst, x, neigh);
        k_gemm1<<<N_NODES / G1_NODES, 128, 0, stream>>>(
            neigh, x, deg + (size_t)t * N_NODES, W1 + (size_t)t * IN_DIM * HID_DIM, h1);
    }
    k_relu<<<(N_NODES * HID_DIM + 255) / 256, 256, 0, stream>>>(h1, b1);

    for (int t = 0; t < N_ETYPES; ++t) {
        const int* src = edges + (size_t)(t * 2 + 0) * N_EDGES;
        const int* dst = edges + (size_t)(t * 2 + 1) * N_EDGES;
        k_gemm2<<<(N_NODES + 31) / 32, 256, 0, stream>>>(
            h1, W2 + (size_t)t * HID_DIM * OUT_DIM, g);
        hipMemsetAsync(neigh, 0, (size_t)N_NODES * OUT_DIM * 4, stream);
        k_scatter2<<<(N_EDGES * OUT_DIM) / 256, 256, 0, stream>>>(src, dst, g, neigh);
        k_accum2<<<(N_NODES * OUT_DIM + 255) / 256, 256, 0, stream>>>(
            neigh, g, deg + (size_t)t * N_NODES, h2);
    }
    k_pool<<<NUM_GRAPHS, 256, 0, stream>>>(h2, gids, b2, out);
}

// Round 2
// 1690.084 us; speedup vs baseline: 1.4257x; 1.4257x over previous
//
#include <hip/hip_runtime.h>

#define N_NODES 100000
#define N_EDGES 800000
#define N_ETYPES 5
#define NUM_GRAPHS 64
#define IN_DIM 23
#define HID_DIM 128
#define OUT_DIM 64
#define CAT_DIM (N_ETYPES * IN_DIM)   // 115
#define CAP 12                        // bucket slots per (etype,node); Poisson(8) tail -> ~13k ovf/etype
#define OVF_CAP 196608

// ---------------- bucketed adjacency fill: pos = atomicAdd(cnt), store src ----------------
__global__ __launch_bounds__(256) void k_fill(const int* __restrict__ edges,
                                              int* __restrict__ cnt,
                                              int* __restrict__ bucket,
                                              int* __restrict__ ovfn,
                                              int* __restrict__ ovf) {
    int e = blockIdx.x * 256 + threadIdx.x;
    int t = blockIdx.y;
    if (e >= N_EDGES) return;
    int src = edges[((size_t)t * 2 + 0) * N_EDGES + e];
    int dst = edges[((size_t)t * 2 + 1) * N_EDGES + e];
    int row = t * N_NODES + dst;
    int pos = atomicAdd(&cnt[row], 1);
    if (pos < CAP) {
        bucket[(size_t)row * CAP + pos] = src;
    } else {
        int oi = atomicAdd(ovfn, 1);
        if (oi < OVF_CAP) { ovf[2 * oi] = row; ovf[2 * oi + 1] = src; }
    }
}

// ---------------- layer-1 gather: 2 nodes per wave, 23 features; writes a_cat scaled ----------------
__global__ __launch_bounds__(256) void k_gather1(const int* __restrict__ cnt,
                                                 const int* __restrict__ bucket,
                                                 const float* __restrict__ x,
                                                 float* __restrict__ acat) {
    int tid = threadIdx.x;
    int n = blockIdx.x * 8 + (tid >> 5);        // 8 half-waves per block
    int f = tid & 31;
    int t = blockIdx.y;
    if (n >= N_NODES) return;
    int row = t * N_NODES + n;
    int c = cnt[row];
    float inv = 1.0f / (float)(c + 1);
    int bval = 0;
    if (f < CAP) bval = bucket[(size_t)row * CAP + f];
    int kmax = c < CAP ? c : CAP;
    float acc = (f < IN_DIM) ? x[(size_t)n * IN_DIM + f] : 0.f;   // gcn self term
    int lanebase = tid & 32;                    // half-wave base within the 64-lane wave
    for (int k = 0; k < CAP; ++k) {
        int src = __shfl(bval, lanebase + k);
        if (k < kmax && f < IN_DIM) acc += x[(size_t)src * IN_DIM + f];
    }
    if (f < IN_DIM) acat[(size_t)n * CAT_DIM + t * IN_DIM + f] = acc * inv;
}

// ---------------- layer-1 overflow: add inv * x[src] into a_cat (rare, exact) ----------------
__global__ __launch_bounds__(256) void k_ovf1(const int* __restrict__ ovfn_p,
                                              const int* __restrict__ ovf,
                                              const int* __restrict__ cnt,
                                              const float* __restrict__ x,
                                              float* __restrict__ acat) {
    int nov = *ovfn_p; if (nov > OVF_CAP) nov = OVF_CAP;
    int wid = (blockIdx.x * 256 + threadIdx.x) >> 6;
    int lane = threadIdx.x & 63;
    int nw = (gridDim.x * 256) >> 6;
    for (int i = wid; i < nov; i += nw) {
        int row = ovf[2 * i], src = ovf[2 * i + 1];
        int t = row / N_NODES;
        int dst = row - t * N_NODES;
        float inv = 1.0f / (float)(cnt[row] + 1);
        if (lane < IN_DIM)
            atomicAdd(&acat[(size_t)dst * CAT_DIM + t * IN_DIM + lane],
                      x[(size_t)src * IN_DIM + lane] * inv);
    }
}

// ---------------- layer-1 GEMM: h1 = relu(a_cat @ W1cat + sum_t b1_t), one shot ----------------
#define GEMM1_NODES 128
__global__ __launch_bounds__(256) void k_gemm1(const float* __restrict__ acat,
                                               const float* __restrict__ W1,
                                               const float* __restrict__ b1,
                                               float* __restrict__ h1) {
    __shared__ float w[CAT_DIM * HID_DIM];      // 58,880 B
    __shared__ float a[2][CAT_DIM];
    int tid = threadIdx.x;
    for (int i = tid; i < CAT_DIM * HID_DIM; i += 256) w[i] = W1[i];
    int j = tid & 127, which = tid >> 7;
    float bsum = 0.f;
    #pragma unroll
    for (int t = 0; t < N_ETYPES; ++t) bsum += b1[t * HID_DIM + j];
    int base = blockIdx.x * GEMM1_NODES;
    for (int it = 0; it < GEMM1_NODES / 2; ++it) {
        int n0 = base + it * 2;
        __syncthreads();
        if ((tid & 127) < CAT_DIM) {
            int n = n0 + which;
            a[which][tid & 127] = (n < N_NODES) ? acat[(size_t)n * CAT_DIM + (tid & 127)] : 0.f;
        }
        __syncthreads();
        int n = n0 + which;
        if (n < N_NODES) {
            float acc = bsum;
            #pragma unroll
            for (int f = 0; f < CAT_DIM; ++f)
                acc = fmaf(a[which][f], w[f * HID_DIM + j], acc);
            h1[(size_t)n * HID_DIM + j] = acc > 0.f ? acc : 0.f;
        }
    }
}

// ---------------- layer-2 GEMM: g = h1 @ W2[t]  (128 -> 64) ----------------
#define G2_ROWS_ITER 4
#define G2_ITERS 8            // 32 rows per block
__global__ __launch_bounds__(256) void k_gemm2(const float* __restrict__ h1,
                                               const float* __restrict__ W2,
                                               float* __restrict__ g) {
    __shared__ float w[HID_DIM * OUT_DIM];      // 32 KiB
    __shared__ float a[G2_ROWS_ITER * HID_DIM];
    for (int i = threadIdx.x; i < HID_DIM * OUT_DIM; i += 256)
        w[i] = W2[i];
    int r = threadIdx.x >> 6;
    int j = threadIdx.x & 63;
    int base = blockIdx.x * (G2_ROWS_ITER * G2_ITERS);
    for (int it = 0; it < G2_ITERS; ++it) {
        int n0 = base + it * G2_ROWS_ITER;
        __syncthreads();
        for (int i = threadIdx.x; i < G2_ROWS_ITER * HID_DIM; i += 256) {
            int rr = i >> 7, ff = i & 127;
            int n = n0 + rr;
            a[i] = (n < N_NODES) ? h1[(size_t)n * HID_DIM + ff] : 0.f;
        }
        __syncthreads();
        int n = n0 + r;
        if (n < N_NODES) {
            float acc = 0.f;
            #pragma unroll
            for (int f = 0; f < HID_DIM; ++f)
                acc = fmaf(a[r * HID_DIM + f], w[f * OUT_DIM + j], acc);
            g[(size_t)n * OUT_DIM + j] = acc;
        }
    }
}

// ---------------- layer-2 gather: wave per node, 64 features; h2 (+)= (sum+self)*inv ----------------
__global__ __launch_bounds__(256) void k_gather2(const int* __restrict__ cnt,
                                                 const int* __restrict__ bucket,
                                                 const float* __restrict__ g,
                                                 float* __restrict__ h2,
                                                 int t, int beta) {
    int n = blockIdx.x * 4 + (threadIdx.x >> 6);
    int lane = threadIdx.x & 63;
    if (n >= N_NODES) return;
    int row = t * N_NODES + n;
    int c = cnt[row];
    float inv = 1.0f / (float)(c + 1);
    int bval = 0;
    if (lane < CAP) bval = bucket[(size_t)row * CAP + lane];
    int kmax = c < CAP ? c : CAP;
    float acc = g[(size_t)n * OUT_DIM + lane];  // self
    for (int k = 0; k < kmax; ++k) {
        int src = __shfl(bval, k);
        acc += g[(size_t)src * OUT_DIM + lane];
    }
    size_t oi = (size_t)n * OUT_DIM + lane;
    float v = acc * inv;
    h2[oi] = beta ? (h2[oi] + v) : v;
}

// ---------------- layer-2 overflow: h2 += inv * g[src] for entries of etype t ----------------
__global__ __launch_bounds__(256) void k_ovf2(const int* __restrict__ ovfn_p,
                                              const int* __restrict__ ovf,
                                              const int* __restrict__ cnt,
                                              const float* __restrict__ g,
                                              float* __restrict__ h2, int t) {
    int nov = *ovfn_p; if (nov > OVF_CAP) nov = OVF_CAP;
    int wid = (blockIdx.x * 256 + threadIdx.x) >> 6;
    int lane = threadIdx.x & 63;
    int nw = (gridDim.x * 256) >> 6;
    int lo = t * N_NODES, hi = lo + N_NODES;
    for (int i = wid; i < nov; i += nw) {
        int row = ovf[2 * i];
        if (row < lo || row >= hi) continue;
        int src = ovf[2 * i + 1];
        int dst = row - lo;
        float inv = 1.0f / (float)(cnt[row] + 1);
        atomicAdd(&h2[(size_t)dst * OUT_DIM + lane],
                  g[(size_t)src * OUT_DIM + lane] * inv);
    }
}

// ---------------- pooling: block = graph, binary-search sorted graph_ids ----------------
__global__ __launch_bounds__(256) void k_pool(const float* __restrict__ h2,
                                              const int* __restrict__ gids,
                                              const float* __restrict__ b2,
                                              float* __restrict__ out) {
    __shared__ float red[4][OUT_DIM];
    int gid = blockIdx.x;
    int lo = 0, hi = N_NODES;
    while (lo < hi) { int mid = (lo + hi) >> 1; if (gids[mid] < gid) lo = mid + 1; else hi = mid; }
    int start = lo;
    hi = N_NODES;
    while (lo < hi) { int mid = (lo + hi) >> 1; if (gids[mid] < gid + 1) lo = mid + 1; else hi = mid; }
    int end = lo;
    int count = end - start;
    int r = threadIdx.x >> 6, j = threadIdx.x & 63;
    float acc = 0.f;
    for (int n = start + r; n < end; n += 4)
        acc += h2[(size_t)n * OUT_DIM + j];
    red[r][j] = acc;
    __syncthreads();
    if (r == 0) {
        float total = red[0][j] + red[1][j] + red[2][j] + red[3][j];
        float b = 0.f;
        #pragma unroll
        for (int t = 0; t < N_ETYPES; ++t) b += b2[t * OUT_DIM + j];
        float c = (float)count;
        out[gid * OUT_DIM + j] = (total + c * b) / fmaxf(c, 1.0f);
    }
}

extern "C" void kernel_launch(void* const* d_in, const int* in_sizes, int n_in,
                              void* d_out, int out_size, void* d_ws, size_t ws_size,
                              hipStream_t stream) {
    const float* x    = (const float*)d_in[0];
    const int*   edges= (const int*)d_in[1];
    const int*   gids = (const int*)d_in[2];
    const float* W1   = (const float*)d_in[3];
    const float* b1   = (const float*)d_in[4];
    const float* W2   = (const float*)d_in[5];
    const float* b2   = (const float*)d_in[6];
    float* out = (float*)d_out;

    // workspace layout (4-byte units), total 32,493,280 words = 129.97 MB
    int*   cnt    = (int*)d_ws;                       // 500,000
    int*   ovfn   = cnt + 500000;                     // 1 (padded to 500,064)
    int*   ovf    = cnt + 500064;                     // 2*OVF_CAP = 393,216
    int*   bucket = cnt + 893280;                     // 5N*CAP = 6,000,000
    float* h1     = (float*)d_ws + 6893280;           // N*128 = 12,800,000
    float* regionA= (float*)d_ws + 19693280;          // 12,800,000 (acat | g+h2)
    float* acat   = regionA;                          // N*115 = 11,500,000 (dead after gemm1)
    float* g      = regionA;                          // N*64
    float* h2     = regionA + (size_t)N_NODES * OUT_DIM; // N*64

    hipMemsetAsync(cnt, 0, 500064 * sizeof(int), stream);   // cnt + ovfn

    dim3 gfill((N_EDGES + 255) / 256, N_ETYPES);
    k_fill<<<gfill, 256, 0, stream>>>(edges, cnt, bucket, ovfn, ovf);

    dim3 gg1(N_NODES / 8, N_ETYPES);                  // 12500 x 5
    k_gather1<<<gg1, 256, 0, stream>>>(cnt, bucket, x, acat);
    k_ovf1<<<1024, 256, 0, stream>>>(ovfn, ovf, cnt, x, acat);
    k_gemm1<<<(N_NODES + GEMM1_NODES - 1) / GEMM1_NODES, 256, 0, stream>>>(acat, W1, b1, h1);

    for (int t = 0; t < N_ETYPES; ++t) {
        k_gemm2<<<(N_NODES + 31) / 32, 256, 0, stream>>>(
            h1, W2 + (size_t)t * HID_DIM * OUT_DIM, g);
        k_gather2<<<N_NODES / 4, 256, 0, stream>>>(cnt, bucket, g, h2, t, t > 0);
        k_ovf2<<<256, 256, 0, stream>>>(ovfn, ovf, cnt, g, h2, t);
    }
    k_pool<<<NUM_GRAPHS, 256, 0, stream>>>(h2, gids, b2, out);
}

// Round 3
// 1008.025 us; speedup vs baseline: 2.3903x; 1.6766x over previous
//
#include <hip/hip_runtime.h>

#define N_NODES 100000
#define N_EDGES 800000
#define N_ETYPES 5
#define NUM_GRAPHS 64
#define IN_DIM 23
#define HID_DIM 128
#define OUT_DIM 64
#define CAT_DIM 115            // 5*23
#define CAP 15                 // srcs per bucket row
#define ROWW 16                // row = [cnt | 15 src] = 64 B
#define OVF_CAP 16384

typedef unsigned short u16;

__device__ __forceinline__ float bf2f(u16 v) {
    union { unsigned u; float f; } x; x.u = ((unsigned)v) << 16; return x.f;
}
__device__ __forceinline__ u16 f2bf(float f) {
    union { float f; unsigned u; } x; x.f = f;
    unsigned r = x.u + 0x7fff + ((x.u >> 16) & 1);   // RNE
    return (u16)(r >> 16);
}

// ---------------- zero bucket cnt words + ovfn ----------------
__global__ __launch_bounds__(256) void k_zero(int* __restrict__ bucket,
                                              int* __restrict__ ovfn) {
    int i = blockIdx.x * 256 + threadIdx.x;
    if (i < N_ETYPES * N_NODES) bucket[(size_t)i * ROWW] = 0;
    if (i == N_ETYPES * N_NODES) *ovfn = 0;
}

// ---------------- adjacency fill: one 64B line per edge ----------------
__global__ __launch_bounds__(256) void k_fill(const int* __restrict__ edges,
                                              int* __restrict__ bucket,
                                              int* __restrict__ ovfn,
                                              long long* __restrict__ ovf) {
    int e = blockIdx.x * 256 + threadIdx.x;
    int t = blockIdx.y;
    if (e >= N_EDGES) return;
    int src = edges[((size_t)t * 2 + 0) * N_EDGES + e];
    int dst = edges[((size_t)t * 2 + 1) * N_EDGES + e];
    int row = t * N_NODES + dst;
    int pos = atomicAdd(&bucket[(size_t)row * ROWW], 1);
    if (pos < CAP) {
        bucket[(size_t)row * ROWW + 1 + pos] = src;
    } else {
        int oi = atomicAdd(ovfn, 1);
        if (oi < OVF_CAP) ovf[oi] = ((long long)row << 32) | (unsigned)src;
    }
}

// ---------------- layer-1 gather: half-wave per (node,etype) ----------------
__global__ __launch_bounds__(256) void k_gather1(const int* __restrict__ bucket,
                                                 const float* __restrict__ x,
                                                 float* __restrict__ acat) {
    int tid = threadIdx.x;
    int n = blockIdx.x * 8 + (tid >> 5);
    int f = tid & 31;
    int t = blockIdx.y;
    int row = t * N_NODES + n;
    const int* brow = bucket + (size_t)row * ROWW;
    int c = brow[0];
    float inv = 1.0f / (float)(c + 1);
    int bval = 0;
    if (f < CAP) bval = brow[1 + f];
    int kmax = c < CAP ? c : CAP;
    float acc = (f < IN_DIM) ? x[(size_t)n * IN_DIM + f] : 0.f;  // gcn self
    int lanebase = tid & 32;
    for (int k = 0; k < kmax; ++k) {
        int src = __shfl(bval, lanebase + k);
        if (f < IN_DIM) acc += x[(size_t)src * IN_DIM + f];
    }
    if (f < IN_DIM) acat[(size_t)n * CAT_DIM + t * IN_DIM + f] = acc * inv;
}

// ---------------- layer-1 overflow (rare, exact) ----------------
__global__ __launch_bounds__(256) void k_ovf1(const int* __restrict__ ovfn,
                                              const long long* __restrict__ ovf,
                                              const int* __restrict__ bucket,
                                              const float* __restrict__ x,
                                              float* __restrict__ acat) {
    int nov = *ovfn; if (nov > OVF_CAP) nov = OVF_CAP;
    int wid = (blockIdx.x * 256 + threadIdx.x) >> 6;
    int lane = threadIdx.x & 63;
    int nw = (gridDim.x * 256) >> 6;
    for (int i = wid; i < nov; i += nw) {
        long long v = ovf[i];
        int row = (int)(v >> 32);
        int src = (int)(v & 0xffffffffLL);
        int t = row / N_NODES;
        int dst = row - t * N_NODES;
        float inv = 1.0f / (float)(bucket[(size_t)row * ROWW] + 1);
        if (lane < IN_DIM)
            atomicAdd(&acat[(size_t)dst * CAT_DIM + t * IN_DIM + lane],
                      x[(size_t)src * IN_DIM + lane] * inv);
    }
}

// ---------------- layer-1 GEMM: h1 = relu(acat @ W1cat + sum_t b1), bf16 out ----------------
__global__ __launch_bounds__(256) void k_gemm1(const float* __restrict__ acat,
                                               const float* __restrict__ W1,
                                               const float* __restrict__ b1,
                                               u16* __restrict__ h1) {
    __shared__ float w[CAT_DIM * HID_DIM];   // 58,880 B
    __shared__ float a[8][CAT_DIM];
    int tid = threadIdx.x;
    for (int i = tid; i < CAT_DIM * HID_DIM; i += 256) w[i] = W1[i];
    int r = tid >> 5;          // 0..7 (row within 8-row tile)
    int jg = tid & 31;         // col group
    int j4 = jg * 4;
    float4 bs = {0.f, 0.f, 0.f, 0.f};
    #pragma unroll
    for (int t = 0; t < N_ETYPES; ++t) {
        bs.x += b1[t * HID_DIM + j4 + 0];
        bs.y += b1[t * HID_DIM + j4 + 1];
        bs.z += b1[t * HID_DIM + j4 + 2];
        bs.w += b1[t * HID_DIM + j4 + 3];
    }
    int base = blockIdx.x * 32;
    for (int it = 0; it < 4; ++it) {
        int n0 = base + it * 8;
        __syncthreads();
        for (int i = tid; i < 8 * CAT_DIM; i += 256) {
            int rr = i / CAT_DIM, ff = i - rr * CAT_DIM;
            a[rr][ff] = acat[(size_t)(n0 + rr) * CAT_DIM + ff];
        }
        __syncthreads();
        float4 acc = bs;
        const float* ar = a[r];
        #pragma unroll
        for (int f = 0; f < CAT_DIM; ++f) {
            float av = ar[f];
            const float4 wv = *(const float4*)&w[f * HID_DIM + j4];
            acc.x = fmaf(av, wv.x, acc.x);
            acc.y = fmaf(av, wv.y, acc.y);
            acc.z = fmaf(av, wv.z, acc.z);
            acc.w = fmaf(av, wv.w, acc.w);
        }
        ushort4 o;
        o.x = f2bf(fmaxf(acc.x, 0.f));
        o.y = f2bf(fmaxf(acc.y, 0.f));
        o.z = f2bf(fmaxf(acc.z, 0.f));
        o.w = f2bf(fmaxf(acc.w, 0.f));
        *(ushort4*)&h1[(size_t)(n0 + r) * HID_DIM + j4] = o;
    }
}

// ---------------- layer-2 fused GEMM: g[tc] = h1 @ W2[t0+tc], bf16 in/out ----------------
#define G2_ROWS 64
__global__ __launch_bounds__(256) void k_gemm2f(const u16* __restrict__ h1,
                                                const float* __restrict__ W2,
                                                u16* __restrict__ g,
                                                int t0, int tcnt) {
    __shared__ float w[HID_DIM * OUT_DIM];   // 32 KiB
    __shared__ float a[G2_ROWS][HID_DIM + 2];// 33.3 KiB, pad vs bank conflicts
    int tid = threadIdx.x;
    int base = blockIdx.x * G2_ROWS;
    for (int i = tid; i < G2_ROWS * HID_DIM / 2; i += 256) {
        int idx = i * 2;
        int rr = idx >> 7, ff = idx & 127;
        int n = base + rr;
        float f0 = 0.f, f1 = 0.f;
        if (n < N_NODES) {
            ushort2 v = *(const ushort2*)&h1[(size_t)n * HID_DIM + ff];
            f0 = bf2f(v.x); f1 = bf2f(v.y);
        }
        a[rr][ff] = f0; a[rr][ff + 1] = f1;
    }
    int r0 = tid >> 4;         // 0..15 -> rows r0, r0+16, r0+32, r0+48
    int jg = tid & 15;
    int j4 = jg * 4;
    for (int tc = 0; tc < tcnt; ++tc) {
        __syncthreads();       // a ready (first) / prev compute done
        const float* W2t = W2 + (size_t)(t0 + tc) * HID_DIM * OUT_DIM;
        for (int i = tid; i < HID_DIM * OUT_DIM; i += 256) w[i] = W2t[i];
        __syncthreads();
        float4 acc0 = {0,0,0,0}, acc1 = {0,0,0,0}, acc2 = {0,0,0,0}, acc3 = {0,0,0,0};
        #pragma unroll 8
        for (int f = 0; f < HID_DIM; ++f) {
            const float4 wv = *(const float4*)&w[f * OUT_DIM + j4];
            float a0 = a[r0][f], a1 = a[r0 + 16][f], a2 = a[r0 + 32][f], a3 = a[r0 + 48][f];
            acc0.x = fmaf(a0, wv.x, acc0.x); acc0.y = fmaf(a0, wv.y, acc0.y);
            acc0.z = fmaf(a0, wv.z, acc0.z); acc0.w = fmaf(a0, wv.w, acc0.w);
            acc1.x = fmaf(a1, wv.x, acc1.x); acc1.y = fmaf(a1, wv.y, acc1.y);
            acc1.z = fmaf(a1, wv.z, acc1.z); acc1.w = fmaf(a1, wv.w, acc1.w);
            acc2.x = fmaf(a2, wv.x, acc2.x); acc2.y = fmaf(a2, wv.y, acc2.y);
            acc2.z = fmaf(a2, wv.z, acc2.z); acc2.w = fmaf(a2, wv.w, acc2.w);
            acc3.x = fmaf(a3, wv.x, acc3.x); acc3.y = fmaf(a3, wv.y, acc3.y);
            acc3.z = fmaf(a3, wv.z, acc3.z); acc3.w = fmaf(a3, wv.w, acc3.w);
        }
        size_t pb = (size_t)tc * N_NODES;
        #pragma unroll
        for (int q = 0; q < 4; ++q) {
            int n = base + r0 + q * 16;
            if (n < N_NODES) {
                float4 acc = q == 0 ? acc0 : q == 1 ? acc1 : q == 2 ? acc2 : acc3;
                ushort4 o;
                o.x = f2bf(acc.x); o.y = f2bf(acc.y); o.z = f2bf(acc.z); o.w = f2bf(acc.w);
                *(ushort4*)&g[(pb + n) * OUT_DIM + j4] = o;
            }
        }
    }
}

// ---------------- layer-2 fused gather: wave per node, all etypes, h2 written once ----------------
__global__ __launch_bounds__(256) void k_gather2f(const int* __restrict__ bucket,
                                                  const u16* __restrict__ g,
                                                  float* __restrict__ h2,
                                                  int t0, int tcnt, int beta) {
    int n = blockIdx.x * 4 + (threadIdx.x >> 6);
    int lane = threadIdx.x & 63;
    float acc = 0.f;
    for (int tc = 0; tc < tcnt; ++tc) {
        int row = (t0 + tc) * N_NODES + n;
        const int* brow = bucket + (size_t)row * ROWW;
        int c = brow[0];
        float inv = 1.0f / (float)(c + 1);
        int bval = 0;
        if (lane < CAP) bval = brow[1 + lane];
        int kmax = c < CAP ? c : CAP;
        const u16* gp = g + (size_t)tc * N_NODES * OUT_DIM;
        float s = bf2f(gp[(size_t)n * OUT_DIM + lane]);   // self
        for (int k = 0; k < kmax; ++k) {
            int src = __shfl(bval, k);
            s += bf2f(gp[(size_t)src * OUT_DIM + lane]);
        }
        acc += s * inv;
    }
    size_t oi = (size_t)n * OUT_DIM + lane;
    h2[oi] = beta ? (h2[oi] + acc) : acc;
}

// ---------------- layer-2 overflow ----------------
__global__ __launch_bounds__(256) void k_ovf2f(const int* __restrict__ ovfn,
                                               const long long* __restrict__ ovf,
                                               const int* __restrict__ bucket,
                                               const u16* __restrict__ g,
                                               float* __restrict__ h2,
                                               int t0, int t1) {
    int nov = *ovfn; if (nov > OVF_CAP) nov = OVF_CAP;
    int wid = (blockIdx.x * 256 + threadIdx.x) >> 6;
    int lane = threadIdx.x & 63;
    int nw = (gridDim.x * 256) >> 6;
    int lo = t0 * N_NODES, hi = t1 * N_NODES;
    for (int i = wid; i < nov; i += nw) {
        long long v = ovf[i];
        int row = (int)(v >> 32);
        if (row < lo || row >= hi) continue;
        int src = (int)(v & 0xffffffffLL);
        int t = row / N_NODES;
        int dst = row - t * N_NODES;
        float inv = 1.0f / (float)(bucket[(size_t)row * ROWW] + 1);
        const u16* gp = g + (size_t)(t - t0) * N_NODES * OUT_DIM;
        atomicAdd(&h2[(size_t)dst * OUT_DIM + lane],
                  bf2f(gp[(size_t)src * OUT_DIM + lane]) * inv);
    }
}

// ---------------- pooling ----------------
__global__ __launch_bounds__(256) void k_pool(const float* __restrict__ h2,
                                              const int* __restrict__ gids,
                                              const float* __restrict__ b2,
                                              float* __restrict__ out) {
    __shared__ float red[4][OUT_DIM];
    int gid = blockIdx.x;
    int lo = 0, hi = N_NODES;
    while (lo < hi) { int mid = (lo + hi) >> 1; if (gids[mid] < gid) lo = mid + 1; else hi = mid; }
    int start = lo;
    hi = N_NODES;
    while (lo < hi) { int mid = (lo + hi) >> 1; if (gids[mid] < gid + 1) lo = mid + 1; else hi = mid; }
    int end = lo;
    int count = end - start;
    int r = threadIdx.x >> 6, j = threadIdx.x & 63;
    float acc = 0.f;
    for (int n = start + r; n < end; n += 4)
        acc += h2[(size_t)n * OUT_DIM + j];
    red[r][j] = acc;
    __syncthreads();
    if (r == 0) {
        float total = red[0][j] + red[1][j] + red[2][j] + red[3][j];
        float b = 0.f;
        #pragma unroll
        for (int t = 0; t < N_ETYPES; ++t) b += b2[t * OUT_DIM + j];
        float c = (float)count;
        out[gid * OUT_DIM + j] = (total + c * b) / fmaxf(c, 1.0f);
    }
}

extern "C" void kernel_launch(void* const* d_in, const int* in_sizes, int n_in,
                              void* d_out, int out_size, void* d_ws, size_t ws_size,
                              hipStream_t stream) {
    const float* x    = (const float*)d_in[0];
    const int*   edges= (const int*)d_in[1];
    const int*   gids = (const int*)d_in[2];
    const float* W1   = (const float*)d_in[3];
    const float* b1   = (const float*)d_in[4];
    const float* W2   = (const float*)d_in[5];
    const float* b2   = (const float*)d_in[6];
    float* out = (float*)d_out;

    // word offsets
    int*       bucket = (int*)d_ws;                               // 8,000,000 (500k x 16)
    int*       ovfn   = bucket + 8000000;                         // 1 (pad to 16)
    long long* ovf    = (long long*)(bucket + 8000016);           // 2*16384 words
    u16*       h1     = (u16*)(bucket + 8032800);                 // 6.4M words
    float*     acat   = (float*)(bucket + 14432800);              // 11.5M words (dead after gemm1)
    u16*       g      = (u16*)acat;                               // planes, 3.2M words each
    size_t need_single = 36832800ULL * 4;                         // 147.3 MB
    bool   single = ws_size >= need_single;
    float* h2 = (float*)(bucket + (single ? 30432800 : 24032800));// 6.4M words

    k_zero<<<(N_ETYPES * N_NODES + 256) / 256, 256, 0, stream>>>(bucket, ovfn);
    k_fill<<<dim3((N_EDGES + 255) / 256, N_ETYPES), 256, 0, stream>>>(edges, bucket, ovfn, ovf);

    k_gather1<<<dim3(N_NODES / 8, N_ETYPES), 256, 0, stream>>>(bucket, x, acat);
    k_ovf1<<<64, 256, 0, stream>>>(ovfn, ovf, bucket, x, acat);
    k_gemm1<<<N_NODES / 32, 256, 0, stream>>>(acat, W1, b1, h1);

    if (single) {
        k_gemm2f<<<(N_NODES + G2_ROWS - 1) / G2_ROWS, 256, 0, stream>>>(h1, W2, g, 0, 5);
        k_gather2f<<<N_NODES / 4, 256, 0, stream>>>(bucket, g, h2, 0, 5, 0);
        k_ovf2f<<<64, 256, 0, stream>>>(ovfn, ovf, bucket, g, h2, 0, 5);
    } else {
        k_gemm2f<<<(N_NODES + G2_ROWS - 1) / G2_ROWS, 256, 0, stream>>>(h1, W2, g, 0, 3);
        k_gather2f<<<N_NODES / 4, 256, 0, stream>>>(bucket, g, h2, 0, 3, 0);
        k_ovf2f<<<64, 256, 0, stream>>>(ovfn, ovf, bucket, g, h2, 0, 3);
        k_gemm2f<<<(N_NODES + G2_ROWS - 1) / G2_ROWS, 256, 0, stream>>>(h1, W2, g, 3, 2);
        k_gather2f<<<N_NODES / 4, 256, 0, stream>>>(bucket, g, h2, 3, 2, 1);
        k_ovf2f<<<64, 256, 0, stream>>>(ovfn, ovf, bucket, g, h2, 3, 5);
    }
    k_pool<<<NUM_GRAPHS, 256, 0, stream>>>(h2, gids, b2, out);
}